// Round 14
// baseline (143.914 us; speedup 1.0000x reference)
//
#include <hip/hip_runtime.h>

typedef __attribute__((ext_vector_type(8))) short bf16x8;
typedef __attribute__((ext_vector_type(8))) unsigned short u16x8;
typedef __attribute__((ext_vector_type(4))) float f32x4;

#define NB 1024
#define NC 64
#define NT 512
#define ND 32

__device__ __forceinline__ unsigned short f2bf(float f) {
  unsigned u = __float_as_uint(f);
  u += 0x7FFFu + ((u >> 16) & 1u);   // round-to-nearest-even (finite values)
  return (unsigned short)(u >> 16);
}
__device__ __forceinline__ float bf2f(unsigned short h) {
  return __uint_as_float(((unsigned)h) << 16);
}

// ---- prep: rearrange weights into MFMA B-fragment order (bf16) ----
// ws layout (ushort elements):
//   [0,16384)      Win  frags [ks(16)][nt(2)][lane(64)][j(8)]   B[k][n], k=32ks+8(l>>4)+j, n=16nt+(l&15)
//   [16384,32768)  Wout frags [nt(32)][lane(64)][j(8)]
//   [32768,33792)  Wq   frags [nt(2)][lane(64)][j(8)]
//   [33792,34816)  Wk   frags
//   [34816,35840)  Wv   frags
__global__ void prep_weights(const float* __restrict__ Win, const float* __restrict__ Wq,
                             const float* __restrict__ Wk, const float* __restrict__ Wv,
                             const float* __restrict__ Wout, unsigned short* __restrict__ ws) {
  int idx = blockIdx.x * 256 + threadIdx.x;
  if (idx >= 35840) return;
  float v;
  if (idx < 16384) {
    int j = idx & 7, lane = (idx >> 3) & 63, nt = (idx >> 9) & 1, ks = idx >> 10;
    int t = 32 * ks + 8 * (lane >> 4) + j;
    int d = 16 * nt + (lane & 15);
    v = Win[t * ND + d];
  } else if (idx < 32768) {
    int p = idx - 16384;
    int j = p & 7, lane = (p >> 3) & 63, nt = (p >> 9) & 31;
    int k = 8 * (lane >> 4) + j;
    int n = 16 * nt + (lane & 15);
    v = Wout[k * NT + n];
  } else {
    int p = idx - 32768;
    const float* W = (p < 1024) ? Wq : ((p < 2048) ? Wk : Wv);
    int q = p & 1023;
    int j = q & 7, lane = (q >> 3) & 63, nt = (q >> 9) & 1;
    int t = 8 * (lane >> 4) + j;
    int d = 16 * nt + (lane & 15);
    v = W[t * ND + d];
  }
  ws[idx] = f2bf(v);
}

// ============ K1: h(16 rows) + q/k/v, grid 4096 = 1024 batches x 4 row-tiles ==
// Wave w computes partial h over K-quarter [128w,128w+128); LDS-reduce; waves
// 0/1/2 emit q/k/v (2 MFMAs each) as bf16 into d_out[b] ushorts [0,6144):
//   q at [0,2048), k at [2048,4096), v at [4096,6144); elem [c*32+d].
__global__ __launch_bounds__(256, 8)
void k_qkv(const float* __restrict__ x, const float* __restrict__ b_in,
           const unsigned short* __restrict__ wsb, float* __restrict__ outb) {
  __shared__ __align__(16) float hp[4][16][32];        // 8 KB partial h
  __shared__ __align__(16) unsigned short hb[16][32];  // 1 KB h bf16
  const int tid = threadIdx.x;
  const int w = tid >> 6, l = tid & 63, g = l >> 4, lo = l & 15;
  const int b = blockIdx.x >> 2, t = blockIdx.x & 3;
  const float* __restrict__ xb = x + (size_t)b * (NC * NT);

  // P1 partial: rows 16t+lo, k in [128w, 128w+128)
  const float* __restrict__ xr = xb + (16 * t + lo) * NT + 128 * w + 8 * g;
  const bf16x8* __restrict__ wsWin = (const bf16x8*)wsb;
  f32x4 zero4 = (f32x4){0.f, 0.f, 0.f, 0.f};
  f32x4 acc0 = zero4, acc1 = zero4;
  f32x4 ra = *(const f32x4*)xr;
  f32x4 rb = *(const f32x4*)(xr + 4);
#pragma unroll
  for (int i = 0; i < 4; ++i) {
    bf16x8 af;
    af[0] = (short)f2bf(ra[0]); af[1] = (short)f2bf(ra[1]);
    af[2] = (short)f2bf(ra[2]); af[3] = (short)f2bf(ra[3]);
    af[4] = (short)f2bf(rb[0]); af[5] = (short)f2bf(rb[1]);
    af[6] = (short)f2bf(rb[2]); af[7] = (short)f2bf(rb[3]);
    int ni = (i < 3) ? (i + 1) : 3;
    f32x4 ra2 = *(const f32x4*)(xr + 32 * ni);
    f32x4 rb2 = *(const f32x4*)(xr + 32 * ni + 4);
    int ks = 4 * w + i;
    acc0 = __builtin_amdgcn_mfma_f32_16x16x32_bf16(af, wsWin[(2 * ks) * 64 + l], acc0, 0, 0, 0);
    acc1 = __builtin_amdgcn_mfma_f32_16x16x32_bf16(af, wsWin[(2 * ks + 1) * 64 + l], acc1, 0, 0, 0);
    ra = ra2; rb = rb2;
  }
#pragma unroll
  for (int r = 0; r < 4; ++r) {
    hp[w][4 * g + r][lo] = acc0[r];
    hp[w][4 * g + r][16 + lo] = acc1[r];
  }
  __syncthreads();
  // reduce 4 partials + bias -> hb (bf16)
#pragma unroll
  for (int e0 = 0; e0 < 2; ++e0) {
    int e = e0 * 256 + tid;
    int r = e >> 5, d = e & 31;
    float s = hp[0][r][d] + hp[1][r][d] + hp[2][r][d] + hp[3][r][d] + b_in[d];
    hb[r][d] = f2bf(s);
  }
  __syncthreads();
  // P2: wave 0->q, 1->k, 2->v (wave 3 idle)
  if (w < 3) {
    const bf16x8* __restrict__ wsW = (const bf16x8*)(wsb + 32768 + 1024 * w);
    bf16x8 ah = *(const bf16x8*)&hb[lo][8 * g];
    unsigned short* __restrict__ u =
        (unsigned short*)(outb + (size_t)b * (NC * NT)) + 2048 * w;
#pragma unroll
    for (int nt = 0; nt < 2; ++nt) {
      f32x4 qa = __builtin_amdgcn_mfma_f32_16x16x32_bf16(ah, wsW[nt * 64 + l], zero4, 0, 0, 0);
#pragma unroll
      for (int r = 0; r < 4; ++r) {
        int c = 16 * t + 4 * g + r;
        u[c * 32 + 16 * nt + lo] = f2bf(qa[r]);
      }
    }
  }
}

// ============ K2: attention, grid 2048 = 1024 batches x 2 halves, 128 thr =====
// Stages qkv (12 KB) from d_out[b] ushorts [0,6144) into LDS; thread owns
// (channel c = 32*half+16w+lo, head hd = g); online no-max softmax; writes
// o-frag bf16x8 to d_out[b] float offset 8192*t (t = c>>4), slot 16*hd + (c&15).
__global__ __launch_bounds__(128, 8)
void k_attn(float* __restrict__ outb) {
  __shared__ __align__(16) unsigned short qkv[6144];   // 12 KB
  const int tid = threadIdx.x;
  const int w = tid >> 6, l = tid & 63, g = l >> 4, lo = l & 15;
  const int b = blockIdx.x >> 1, half = blockIdx.x & 1;
  unsigned short* __restrict__ u = (unsigned short*)(outb + (size_t)b * (NC * NT));
#pragma unroll
  for (int i = 0; i < 6; ++i) {
    int idx = i * 128 + tid;
    *(u16x8*)&qkv[8 * idx] = *(const u16x8*)&u[8 * idx];
  }
  __syncthreads();
  const int c = 32 * half + 16 * w + lo;
  const int hd = g;
  float qv[8];
  {
    u16x8 q8 = *(const u16x8*)&qkv[c * 32 + 8 * hd];
#pragma unroll
    for (int j = 0; j < 8; ++j) qv[j] = bf2f(q8[j]);
  }
  float sum = 0.f;
  float ov[8] = {0.f, 0.f, 0.f, 0.f, 0.f, 0.f, 0.f, 0.f};
#pragma unroll 4
  for (int kk = 0; kk < 64; ++kk) {
    u16x8 k8 = *(const u16x8*)&qkv[2048 + kk * 32 + 8 * hd];
    float s = 0.f;
#pragma unroll
    for (int j = 0; j < 8; ++j) s += qv[j] * bf2f(k8[j]);
    float p = exp2f(s * (1.4426950408889634f * 0.35355339059327373f));
    sum += p;
    u16x8 v8 = *(const u16x8*)&qkv[4096 + kk * 32 + 8 * hd];
#pragma unroll
    for (int j = 0; j < 8; ++j) ov[j] += p * bf2f(v8[j]);
  }
  float inv = 1.0f / sum;
  bf16x8 o8;
#pragma unroll
  for (int j = 0; j < 8; ++j) o8[j] = (short)f2bf(ov[j] * inv);
  const int tt = 2 * half + w;   // = c >> 4
  bf16x8* __restrict__ stash = (bf16x8*)(outb + (size_t)b * (NC * NT) + 8192 * tt);
  stash[16 * g + lo] = o8;
}

// ============ K3: y = o @ Wout + b_out + x, LayerNorm; grid 4096 ==============
// Block (b,t): rows 16t..16t+15, all 512 cols. o-frag read from float offset
// 8192*t of own region (overwritten only after the LN __syncthreads -> safe).
__global__ __launch_bounds__(256, 8)
void k_out(const float* __restrict__ x, const float* __restrict__ b_out,
           const float* __restrict__ gamma, const float* __restrict__ beta,
           const unsigned short* __restrict__ wsb, float* __restrict__ out) {
  __shared__ float red0[4][16];
  __shared__ float red1[4][16];
  __shared__ float mu_a[16], rs_a[16];
  const int tid = threadIdx.x;
  const int w = tid >> 6, l = tid & 63, g = l >> 4, lo = l & 15;
  const int b = blockIdx.x >> 2, t = blockIdx.x & 3;
  const float* __restrict__ xb = x + (size_t)b * (NC * NT);
  float* __restrict__ ob = out + (size_t)b * (NC * NT);

  const bf16x8 a4 = ((const bf16x8*)(ob + 8192 * t))[l];
  const bf16x8* __restrict__ wsWout = (const bf16x8*)(wsb + 16384);
  f32x4 zero4 = (f32x4){0.f, 0.f, 0.f, 0.f};
  const int colbase = 128 * w + lo;
  const float* __restrict__ xrow = xb + (16 * t + 4 * g) * NT + colbase;

  float s1[4] = {0.f, 0.f, 0.f, 0.f};
  float s2[4] = {0.f, 0.f, 0.f, 0.f};
#pragma unroll 4
  for (int p = 0; p < 8; ++p) {
    bf16x8 bfr = wsWout[(8 * w + p) * 64 + l];
    f32x4 acc = __builtin_amdgcn_mfma_f32_16x16x32_bf16(a4, bfr, zero4, 0, 0, 0);
    int col = 16 * p;
    float bo = b_out[colbase + col];
#pragma unroll
    for (int r = 0; r < 4; ++r) {
      float y = acc[r] + bo + xrow[r * NT + col];
      s1[r] += y;
      s2[r] += y * y;
    }
  }
#pragma unroll
  for (int off = 1; off <= 8; off <<= 1)
#pragma unroll
    for (int r = 0; r < 4; ++r) {
      s1[r] += __shfl_xor(s1[r], off, 64);
      s2[r] += __shfl_xor(s2[r], off, 64);
    }
#pragma unroll
  for (int r = 0; r < 4; ++r)
    if (lo == r) { red0[w][4 * g + r] = s1[r]; red1[w][4 * g + r] = s2[r]; }
  __syncthreads();
  if (tid < 16) {
    float s = red0[0][tid] + red0[1][tid] + red0[2][tid] + red0[3][tid];
    float q2 = red1[0][tid] + red1[1][tid] + red1[2][tid] + red1[3][tid];
    float mu = s * (1.0f / 512.0f);
    float var = q2 * (1.0f / 512.0f) - mu * mu;
    mu_a[tid] = mu;
    rs_a[tid] = rsqrtf(var + 1e-5f);
  }
  __syncthreads();
  float* __restrict__ orow = ob + (16 * t + 4 * g) * NT + colbase;
#pragma unroll 4
  for (int p = 0; p < 8; ++p) {
    bf16x8 bfr = wsWout[(8 * w + p) * 64 + l];
    f32x4 acc = __builtin_amdgcn_mfma_f32_16x16x32_bf16(a4, bfr, zero4, 0, 0, 0);
    int col = 16 * p;
    float bo = b_out[colbase + col];
    float gm = gamma[colbase + col];
    float bt = beta[colbase + col];
#pragma unroll
    for (int r = 0; r < 4; ++r) {
      float y = acc[r] + bo + xrow[r * NT + col];
      int row4 = 4 * g + r;
      orow[r * NT + col] = (y - mu_a[row4]) * rs_a[row4] * gm + bt;
    }
  }
}

extern "C" void kernel_launch(void* const* d_in, const int* in_sizes, int n_in,
                              void* d_out, int out_size, void* d_ws, size_t ws_size,
                              hipStream_t stream) {
  const float* x     = (const float*)d_in[0];
  const float* W_in  = (const float*)d_in[1];
  const float* b_in  = (const float*)d_in[2];
  const float* W_q   = (const float*)d_in[3];
  const float* W_k   = (const float*)d_in[4];
  const float* W_v   = (const float*)d_in[5];
  const float* W_out = (const float*)d_in[6];
  const float* b_out = (const float*)d_in[7];
  const float* gamma = (const float*)d_in[8];
  const float* beta  = (const float*)d_in[9];
  unsigned short* ws = (unsigned short*)d_ws;

  prep_weights<<<140, 256, 0, stream>>>(W_in, W_q, W_k, W_v, W_out, ws);
  k_qkv<<<4096, 256, 0, stream>>>(x, b_in, ws, (float*)d_out);
  k_attn<<<2048, 128, 0, stream>>>((float*)d_out);
  k_out<<<4096, 256, 0, stream>>>(x, b_out, gamma, beta, ws, (float*)d_out);
}